// Round 6
// baseline (571.197 us; speedup 1.0000x reference)
//
#include <hip/hip_runtime.h>
#include <math.h>

namespace {
constexpr int B_ = 4;
constexpr int N_ = 2048;
constexpr int K_ = 48;
constexpr int MAX_REL_ = 32;
constexpr int EDGE_C_ = 128;
constexpr int PE_IN_ = 66;    // 2*MAX_REL + 2
constexpr int NUM_PE_ = 16;
constexpr int NROWS = B_ * N_;      // 8192
constexpr int NEDGE = NROWS * K_;   // 393216
}

// ---------------- kernel 1: X = coords[center] * mask  (SoA output) ---------
__global__ __launch_bounds__(256) void x_kernel(const float* __restrict__ coords,
                                                const float* __restrict__ mask,
                                                const int* __restrict__ t2ca,
                                                float* __restrict__ Xx,
                                                float* __restrict__ Xy,
                                                float* __restrict__ Xz) {
    int r = blockIdx.x * 256 + threadIdx.x;
    if (r >= NROWS) return;
    int b = r >> 11;                 // N_ = 2048
    int c = t2ca[r];
    float m = mask[r];
    const float* s = coords + ((size_t)(b * N_ + c)) * 3;
    Xx[r] = __fmul_rn(s[0], m);
    Xy[r] = __fmul_rn(s[1], m);
    Xz[r] = __fmul_rn(s[2], m);
}

// ---------------- kernel 2: masked distances + stable top-K (smallest) --------
// One wave per row, 4 rows/block. Distances in REGISTERS (no LDS).
// f32 keys, chain: d2 = fma(dz,dz, fma(dx,dx, dy*dy)); d = m2*sqrt(d2+1e-6).
// Ties: LOWER index first (verified vs np-host reference, R5 pass).
__global__ __launch_bounds__(256) void knn_kernel(const float* __restrict__ Xx,
                                                  const float* __restrict__ Xy,
                                                  const float* __restrict__ Xz,
                                                  const float* __restrict__ mask,
                                                  float* __restrict__ eidx_f,
                                                  float* __restrict__ dneb) {
    const int lane = threadIdx.x & 63;
    const int row = blockIdx.x * 4 + (threadIdx.x >> 6);
    const int b = row >> 11;
    const int base = b * N_;

    const float xi0 = Xx[row];
    const float xi1 = Xy[row];
    const float xi2 = Xz[row];
    const float mi = mask[row];
    const float* mb = mask + base;

    float vals[32];

    // pass 1: D = m2 * sqrt(fma-chain + 1e-6), row max
    float lmax = -INFINITY;
    #pragma unroll
    for (int t = 0; t < 32; ++t) {
        int j = t * 64 + lane;
        float dx = __fsub_rn(xi0, Xx[base + j]);
        float dy = __fsub_rn(xi1, Xy[base + j]);
        float dz = __fsub_rn(xi2, Xz[base + j]);
        float d2 = __fmaf_rn(dz, dz, __fmaf_rn(dx, dx, __fmul_rn(dy, dy)));
        float m2 = __fmul_rn(mi, mb[j]);
        float d = __fmul_rn(m2, __fsqrt_rn(__fadd_rn(d2, 1e-6f)));
        vals[t] = d;
        lmax = fmaxf(lmax, d);
    }
    #pragma unroll
    for (int off = 32; off; off >>= 1) lmax = fmaxf(lmax, __shfl_xor(lmax, off, 64));

    // pass 2: D_adjust = D + (1-m2)*Dmax; per-lane chunk argmin (lowest t wins)
    float cv = INFINITY; int ci = 0;
    #pragma unroll
    for (int t = 0; t < 32; ++t) {
        int j = t * 64 + lane;
        float m2 = __fmul_rn(mi, mb[j]);
        float d = __fadd_rn(vals[t], __fmul_rn(__fsub_rn(1.0f, m2), lmax));
        vals[t] = d;
        if (d < cv) { cv = d; ci = t; }
    }

    // 48 rounds: global lexicographic (val asc, idx asc) min; register rescan.
    float keep_v = 0.0f; int keep_i = 0;
    for (int k = 0; k < K_; ++k) {
        float v = cv; int idx = ci * 64 + lane;
        #pragma unroll
        for (int off = 32; off; off >>= 1) {
            float ov = __shfl_xor(v, off, 64);
            int oi = __shfl_xor(idx, off, 64);
            if (ov < v || (ov == v && oi < idx)) { v = ov; idx = oi; }
        }
        if (lane == k) { keep_v = v; keep_i = idx; }

        // removal: idx is wave-uniform after the reduction
        int idx_s = __builtin_amdgcn_readfirstlane(idx);
        int t_rm = idx_s >> 6;          // scalar
        bool iam = (lane == (idx_s & 63));
        #pragma unroll
        for (int t = 0; t < 32; ++t)
            if (t == t_rm && iam) vals[t] = INFINITY;   // scalar-guarded cndmask

        // rescan (all lanes; non-owners recompute unchanged result)
        cv = vals[0]; ci = 0;
        #pragma unroll
        for (int t = 1; t < 32; ++t)
            if (vals[t] < cv) { cv = vals[t]; ci = t; }
    }
    if (lane < K_) {
        dneb[(size_t)row * K_ + lane] = keep_v;
        eidx_f[(size_t)row * K_ + lane] = (float)keep_i;   // exact int-in-float
    }
}

// ---------------- kernel 3: features -> 33x128 matmul -> LayerNorm ----------
// TWO edges per wave iteration (pair shares the row since K=48 is even):
// 4 independent FMA/LN chains + 2 gather chains overlap memory latency.
__global__ __launch_bounds__(256) void edge_kernel(const float* __restrict__ eidx_f,
                                                   const float* __restrict__ dneb,
                                                   const float* __restrict__ token_bonds,
                                                   const float* __restrict__ pe_w,
                                                   const float* __restrict__ pe_b,
                                                   const float* __restrict__ edge_w,
                                                   const float* __restrict__ ln_g,
                                                   const float* __restrict__ ln_b,
                                                   const int* __restrict__ res_idx,
                                                   const int* __restrict__ is_lig,
                                                   float* __restrict__ Eout) {
    __shared__ float4 s_pe[PE_IN_ * 4];   // pe_w[d,:] + pe_b, 16 floats per d
    const int tid = threadIdx.x;
    for (int idx = tid; idx < PE_IN_ * NUM_PE_; idx += 256) {
        ((float*)s_pe)[idx] = pe_w[idx] + pe_b[idx & 15];
    }
    __syncthreads();

    const int lane = tid & 63;
    // W columns -> registers (66 VGPRs), constant over the edge loop
    float w0[33], w1[33];
    #pragma unroll
    for (int p = 0; p < 33; ++p) {
        float2 w = ((const float2*)edge_w)[p * 64 + lane];
        w0[p] = w.x; w1[p] = w.y;
    }
    const float g0 = ln_g[2 * lane], g1 = ln_g[2 * lane + 1];
    const float bb0 = ln_b[2 * lane], bb1 = ln_b[2 * lane + 1];

    const float mu_r = 2.0f + (float)(lane & 15) * (20.0f / 15.0f);

    const int gwave = blockIdx.x * 4 + (tid >> 6);
    const int nwaves = gridDim.x * 4;               // 12288
    constexpr int NPAIR = NEDGE / 2;                // 196608 = 12288*16

    for (int e2 = gwave; e2 < NPAIR; e2 += nwaves) {
        const int e0 = e2 * 2, e1 = e0 + 1;
        const int row = e2 / 24;                    // = e0/48; pair shares row
        const int b = row >> 11;

        float2 eif = ((const float2*)eidx_f)[e2];
        float2 Dp  = ((const float2*)dneb)[e2];
        const int j0 = (int)(eif.x + 0.5f);
        const int j1 = (int)(eif.y + 0.5f);

        const int ri = res_idx[row];
        const int li = is_lig[row];
        const int jr0 = b * N_ + j0, jr1 = b * N_ + j1;
        const int rj0 = res_idx[jr0], rj1 = res_idx[jr1];
        const int lj0 = is_lig[jr0], lj1 = is_lig[jr1];
        float tb0 = token_bonds[(size_t)row * N_ + j0];
        float tb1 = token_bonds[(size_t)row * N_ + j1];
        tb0 = (li | lj0) ? tb0 : 0.0f;
        tb1 = (li | lj1) ? tb1 : 0.0f;
        const int d0 = min(max(ri - rj0 + MAX_REL_, 0), 2 * MAX_REL_);
        const int d1 = min(max(ri - rj1 + MAX_REL_, 0), 2 * MAX_REL_);

        float f0[33], f1[33];
        {
            float4 a0 = s_pe[d0 * 4 + 0], a1 = s_pe[d0 * 4 + 1];
            float4 a2 = s_pe[d0 * 4 + 2], a3 = s_pe[d0 * 4 + 3];
            f0[0]=a0.x; f0[1]=a0.y; f0[2]=a0.z; f0[3]=a0.w;
            f0[4]=a1.x; f0[5]=a1.y; f0[6]=a1.z; f0[7]=a1.w;
            f0[8]=a2.x; f0[9]=a2.y; f0[10]=a2.z; f0[11]=a2.w;
            f0[12]=a3.x; f0[13]=a3.y; f0[14]=a3.z; f0[15]=a3.w;
            float4 c0 = s_pe[d1 * 4 + 0], c1 = s_pe[d1 * 4 + 1];
            float4 c2 = s_pe[d1 * 4 + 2], c3 = s_pe[d1 * 4 + 3];
            f1[0]=c0.x; f1[1]=c0.y; f1[2]=c0.z; f1[3]=c0.w;
            f1[4]=c1.x; f1[5]=c1.y; f1[6]=c1.z; f1[7]=c1.w;
            f1[8]=c2.x; f1[9]=c2.y; f1[10]=c2.z; f1[11]=c2.w;
            f1[12]=c3.x; f1[13]=c3.y; f1[14]=c3.z; f1[15]=c3.w;
        }

        // RBF: each lane computes its bucket's exp for both edges, then
        // distributes within its 16-lane group (independent shuffle streams).
        float t0 = (Dp.x - mu_r) * 0.8f;
        float t1 = (Dp.y - mu_r) * 0.8f;
        float ex0 = __expf(-t0 * t0);
        float ex1 = __expf(-t1 * t1);
        const int gbase = lane & 48;
        #pragma unroll
        for (int rr = 0; rr < 16; ++rr) {
            f0[16 + rr] = __shfl(ex0, gbase | rr, 64);
            f1[16 + rr] = __shfl(ex1, gbase | rr, 64);
        }
        f0[32] = tb0; f1[32] = tb1;

        float ax0 = 0.f, ay0 = 0.f, ax1 = 0.f, ay1 = 0.f;
        #pragma unroll
        for (int p = 0; p < 33; ++p) {
            ax0 = fmaf(f0[p], w0[p], ax0);
            ay0 = fmaf(f0[p], w1[p], ay0);
            ax1 = fmaf(f1[p], w0[p], ax1);
            ay1 = fmaf(f1[p], w1[p], ay1);
        }

        // LayerNorm over 128 channels (2/lane), both edges interleaved
        float s0 = ax0 + ay0, q0 = ax0 * ax0 + ay0 * ay0;
        float s1 = ax1 + ay1, q1 = ax1 * ax1 + ay1 * ay1;
        #pragma unroll
        for (int off = 32; off; off >>= 1) {
            s0 += __shfl_xor(s0, off, 64);
            q0 += __shfl_xor(q0, off, 64);
            s1 += __shfl_xor(s1, off, 64);
            q1 += __shfl_xor(q1, off, 64);
        }
        float mu0 = s0 * (1.0f / 128.0f);
        float mu1 = s1 * (1.0f / 128.0f);
        float r0 = rsqrtf(q0 * (1.0f / 128.0f) - mu0 * mu0 + 1e-5f);
        float r1 = rsqrtf(q1 * (1.0f / 128.0f) - mu1 * mu1 + 1e-5f);
        float2 o0 = make_float2((ax0 - mu0) * r0 * g0 + bb0,
                                (ay0 - mu0) * r0 * g1 + bb1);
        float2 o1 = make_float2((ax1 - mu1) * r1 * g0 + bb0,
                                (ay1 - mu1) * r1 * g1 + bb1);
        ((float2*)Eout)[(size_t)e0 * 64 + lane] = o0;
        ((float2*)Eout)[(size_t)e1 * 64 + lane] = o1;
    }
}

extern "C" void kernel_launch(void* const* d_in, const int* in_sizes, int n_in,
                              void* d_out, int out_size, void* d_ws, size_t ws_size,
                              hipStream_t stream) {
    const float* coords      = (const float*)d_in[0];
    const float* mask        = (const float*)d_in[1];
    const float* token_bonds = (const float*)d_in[2];
    const float* pe_w        = (const float*)d_in[3];
    const float* pe_b        = (const float*)d_in[4];
    const float* edge_w      = (const float*)d_in[5];
    const float* ln_g        = (const float*)d_in[6];
    const float* ln_b        = (const float*)d_in[7];
    const int*   t2ca        = (const int*)d_in[8];
    const int*   res_idx     = (const int*)d_in[9];
    // d_in[10] (asym_id) unused: chain_labels = zeros in the reference
    const int*   is_lig      = (const int*)d_in[11];

    float* out    = (float*)d_out;
    float* Eout   = out;                               // NEDGE * 128
    float* eidx_f = out + (size_t)NEDGE * EDGE_C_;     // NEDGE (ints as floats)
    float* dneb   = eidx_f + NEDGE;                    // NEDGE

    float* Xx = (float*)d_ws;                          // SoA, 3*NROWS floats
    float* Xy = Xx + NROWS;
    float* Xz = Xy + NROWS;

    hipLaunchKernelGGL(x_kernel, dim3(NROWS / 256), dim3(256), 0, stream,
                       coords, mask, t2ca, Xx, Xy, Xz);
    hipLaunchKernelGGL(knn_kernel, dim3(NROWS / 4), dim3(256), 0, stream,
                       Xx, Xy, Xz, mask, eidx_f, dneb);
    hipLaunchKernelGGL(edge_kernel, dim3(3072), dim3(256), 0, stream,
                       eidx_f, dneb, token_bonds, pe_w, pe_b, edge_w,
                       ln_g, ln_b, res_idx, is_lig, Eout);
}